// Round 15
// baseline (336.655 us; speedup 1.0000x reference)
//
#include <hip/hip_runtime.h>
#include <hip/hip_bf16.h>

// Grouped conv2d as implicit GEMM per group:
//   out[b*64+co][h][w] = sum_{ci,kh,kw} W[b*64+co][ci][kh][kw] * x[b*64+ci][h+kh-1][w+kw-1]
// bf16 MFMA (16x16x32), fp32 accumulate.
//
// R15 = R13 (best: 335us rocprof / 289.6 bench, 96 VGPR, clean) + co-split
// waves for 2x resident waves/CU:
//  - block 512 thr = 8 waves = (4 output rows x 2 co-halves). R11's verified
//    co-split algebra: acc[2][4]=32 VGPR; epilogue co=(ch*2+mtl)*16+...
//  - afs broadcast unchanged (R13); per-wave af ds_reads halve (18 frags).
//  - staging = R13's verified ping-pong spread over 8 waves (3 rows/thread,
//    16 live floats) + R13's 48-thread halo path verbatim.
//  - LDS 25.3+36.9 = 62.2KB -> 2 blocks/CU = 16 waves/CU (50% cap) vs
//    R13's 8 waves (20.5% measured). No __launch_bounds__ VGPR gamble.

typedef __bf16 bf16x8 __attribute__((ext_vector_type(8)));
typedef float  f32x4  __attribute__((ext_vector_type(4)));

#define NB 32
#define NH 256
#define NW 256
#define TILE_H 4
#define TILE_W 64
#define XROWS 6     // TILE_H + 2 (halo)
#define XCOLS 66    // col 0 = w0-1, col 65 = w0+64
#define HWSZ ((size_t)NH * NW)

__device__ __forceinline__ void gload16(const float* g, float* lds) {
    __builtin_amdgcn_global_load_lds(
        (const __attribute__((address_space(1))) unsigned int*)g,
        (__attribute__((address_space(3))) unsigned int*)lds, 16, 0, 0);
}

// ---------------------------------------------------------------------------
// Repack weights into MFMA A-fragment order:
//   pk[((b*9+tap)*4+mt)*2+kc][lane][j]  (bf16, 16B per lane)
// value = W[b*64 + mt*16 + (lane&15)][kc*32 + (lane>>4)*8 + j][tap]
// ---------------------------------------------------------------------------
__global__ void repack_weights_kernel(const float* __restrict__ wsrc,
                                      __bf16* __restrict__ pk) {
    int t = blockIdx.x * blockDim.x + threadIdx.x;
    if (t >= NB * 9 * 4 * 2 * 64) return;
    int lane = t & 63;
    int r = t >> 6;
    int kc = r & 1;  r >>= 1;
    int mt = r & 3;  r >>= 2;
    int tap = r % 9;
    int b   = r / 9;
    int co  = b * 64 + mt * 16 + (lane & 15);
    int ci0 = kc * 32 + (lane >> 4) * 8;
    bf16x8 v;
#pragma unroll
    for (int j = 0; j < 8; ++j) {
        v[j] = (__bf16)wsrc[(co * 64 + ci0 + j) * 9 + tap];
    }
    *reinterpret_cast<bf16x8*>(pk + (size_t)t * 8) = v;
}

// ---------------------------------------------------------------------------
// Main conv kernel. Block = (group b, 4 output rows, 64 cols), 8 waves.
// Wave wid: output row rloc = wid>>1, co-half ch = wid&1 (32 co).
// xs: [r][c][32] bf16, octet o of col c at 8*(o ^ ((c>>1)&3)).
// afs: 36 frags (tap*4+mt) x 512 bf16 lane-linear, refilled per kc phase.
// ---------------------------------------------------------------------------
__launch_bounds__(512)
__global__ void conv_mfma_kernel(const float* __restrict__ x,
                                 const __bf16* __restrict__ pk,
                                 float* __restrict__ out) {
    __shared__ __align__(16) __bf16 xs[XROWS * XCOLS * 32];   // 25344 B
    __shared__ __align__(16) __bf16 afs[36 * 512];            // 36864 B

    // XCD-aware bijective swizzle: 8192 blocks, 8 XCDs -> 1024-chunk per XCD
    const int orig = blockIdx.x;
    const int wg   = (orig & 7) * 1024 + (orig >> 3);
    const int b    = wg >> 8;            // 0..31
    const int by   = (wg >> 2) & 63;     // 0..63
    const int bx   = wg & 3;             // 0..3
    const int h0   = by * TILE_H;
    const int w0   = bx * TILE_W;

    const int tid  = threadIdx.x;
    const int wid  = tid >> 6;           // 0..7
    const int lane = tid & 63;
    const int nl   = lane & 15;
    const int kgrp = lane >> 4;          // 0..3
    const int rloc = wid >> 1;           // output row 0..3
    const int ch   = wid & 1;            // co-half

    const char* pkb = (const char*)(pk + (size_t)b * 9 * 4096);

    // ---- af copy for phase kcv: 36 x 1KB gload16 over 8 waves (4-5 each) ----
    auto issue_af = [&](int kcv) {
#pragma unroll
        for (int i = 0; i < 5; ++i) {
            const int f = wid + i * 8;        // 0..39, skip >=36
            if (f < 36) {
                const int tp = f >> 2;
                const int mt = f & 3;
                const float* src = (const float*)(pkb + tp * 8192
                                                  + (mt * 2 + kcv) * 1024 + lane * 16);
                gload16(src, (float*)((char*)afs + f * 1024));
            }
        }
    };

    f32x4 acc[2][4];   // [mtl][q]
#pragma unroll
    for (int mtl = 0; mtl < 2; ++mtl)
#pragma unroll
        for (int q = 0; q < 4; ++q)
            acc[mtl][q] = (f32x4){0.f, 0.f, 0.f, 0.f};

    // staging constants: thread = (column c = lane, oct = wid&3,
    // row-third = wid>>2 -> rows rbase..rbase+2)
    const int c     = lane;              // 0..63 -> w = w0-1+c
    const int w     = w0 - 1 + c;
    const int wcl   = min(max(w, 0), NW - 1);
    const bool wbad = (w != wcl);
    const int oct   = wid & 3;
    const int rbase = (wid >> 2) * 3;    // 0 or 3
    const int sciw  = ((oct ^ ((c >> 1) & 3)) * 8);   // swizzled octet offset

    // halo constants (threads 0..47: c=64,65; 6 rows x 2 sides x 4 oct)
    const int hr    = tid >> 3;              // 0..5
    const int hside = (tid >> 2) & 1;        // 0,1 -> c = 64,65
    const int hoct  = tid & 3;               // local ci octet
    const int hch   = 64 + hside;
    const int hw    = w0 + 63 + hside;
    const int hwc   = min(hw, NW - 1);

#pragma unroll
    for (int kc = 0; kc < 2; ++kc) {
        // ---- stage phase kc: af copy (fire-and-forget) + 32-ci x tile ----
        {
            issue_af(kc);

            const int cibase = b * 64 + kc * 32 + oct * 8;
            const float* colp = x + (size_t)cibase * HWSZ + wcl;

            // halo loads first (threads 0..47), store at end
            float hv[8];
            if (tid < 48) {
                const int h  = h0 - 1 + hr;
                const int hc = min(max(h, 0), NH - 1);
                const float* src = x + ((size_t)(b * 64 + kc * 32 + hoct * 8) * NH + hc) * NW + hwc;
#pragma unroll
                for (int j = 0; j < 8; ++j) hv[j] = src[j * HWSZ];
                if (h != hc || hw != hwc) {
#pragma unroll
                    for (int j = 0; j < 8; ++j) hv[j] = 0.f;
                }
            }

            float va[8], vb[8];
            auto load8 = [&](int k, float* v) {   // k = 0..2, row rbase+k
                const int h  = h0 - 1 + rbase + k;
                const int hc = min(max(h, 0), NH - 1);
                const float* src = colp + (size_t)hc * NW;
#pragma unroll
                for (int j = 0; j < 8; ++j) v[j] = src[j * HWSZ];
                if (wbad || h != hc) {
#pragma unroll
                    for (int j = 0; j < 8; ++j) v[j] = 0.f;
                }
            };
            auto store8 = [&](int k, const float* v) {
                bf16x8 o;
#pragma unroll
                for (int j = 0; j < 8; ++j) o[j] = (__bf16)v[j];
                *reinterpret_cast<bf16x8*>(xs + ((rbase + k) * XCOLS + c) * 32 + sciw) = o;
            };

            load8(0, va);
            load8(1, vb);
            store8(0, va); load8(2, va);
            store8(1, vb);
            store8(2, va);

            if (tid < 48) {
                bf16x8 o;
#pragma unroll
                for (int j = 0; j < 8; ++j) o[j] = (__bf16)hv[j];
                // slot(64)=slot(65)=0 -> octet position = hoct
                *reinterpret_cast<bf16x8*>(xs + (hr * XCOLS + hch) * 32 + hoct * 8) = o;
            }
        }
        __syncthreads();    // drains vmcnt: afs + xs both ready

        // ---- compute phase kc: 9 taps, VMEM-silent; af via ds_read_b128 ----
#pragma unroll
        for (int tap = 0; tap < 9; ++tap) {
            bf16x8 afr[2];
#pragma unroll
            for (int mtl = 0; mtl < 2; ++mtl)
                afr[mtl] = *reinterpret_cast<const bf16x8*>(
                    afs + (tap * 4 + ch * 2 + mtl) * 512 + lane * 8);
            const int kh = tap / 3;
            const int kw = tap - kh * 3;
            const int rowbase = (rloc + kh) * XCOLS;
#pragma unroll
            for (int q = 0; q < 4; ++q) {
                const int cc   = q * 16 + nl + kw;          // 0..65
                const int slot = (cc >> 1) & 3;
                bf16x8 bfv = *reinterpret_cast<const bf16x8*>(
                    xs + (rowbase + cc) * 32 + ((kgrp ^ slot) * 8));
#pragma unroll
                for (int mtl = 0; mtl < 2; ++mtl)
                    acc[mtl][q] = __builtin_amdgcn_mfma_f32_16x16x32_bf16(
                        afr[mtl], bfv, acc[mtl][q], 0, 0, 0);
            }
        }
        if (kc == 0) __syncthreads();   // protect xs/afs before phase-1 refill
    }

    // ---- epilogue: D lane layout col=lane&15, row=(lane>>4)*4+reg ----
    const int mrow = kgrp * 4;
    const int h = h0 + rloc;
#pragma unroll
    for (int mtl = 0; mtl < 2; ++mtl) {
#pragma unroll
        for (int q = 0; q < 4; ++q) {
            const int ww = w0 + q * 16 + nl;
#pragma unroll
            for (int rg = 0; rg < 4; ++rg) {
                const int co = (ch * 2 + mtl) * 16 + mrow + rg;
                out[((size_t)(b * 64 + co) * NH + h) * NW + ww] = acc[mtl][q][rg];
            }
        }
    }
}

extern "C" void kernel_launch(void* const* d_in, const int* in_sizes, int n_in,
                              void* d_out, int out_size, void* d_ws, size_t ws_size,
                              hipStream_t stream) {
    const float* x = (const float*)d_in[0];     // [1, 32*64, 256, 256] fp32
    const float* w = (const float*)d_in[1];     // [2048, 64, 3, 3] fp32
    float* out = (float*)d_out;                 // [1, 2048, 256, 256] fp32
    __bf16* pk = (__bf16*)d_ws;                 // 2.25 MB repacked bf16 weights

    {
        int total = NB * 9 * 4 * 2 * 64;        // 147456
        int blk = 256;
        int grid = (total + blk - 1) / blk;     // 576
        hipLaunchKernelGGL(repack_weights_kernel, dim3(grid), dim3(blk), 0, stream,
                           w, pk);
    }
    {
        dim3 grid(8192);                        // 32b x 64by x 4bx, swizzled
        hipLaunchKernelGGL(conv_mfma_kernel, grid, dim3(512), 0, stream,
                           x, pk, out);
    }
}

// Round 16
// 296.626 us; speedup vs baseline: 1.1349x; 1.1349x over previous
//
#include <hip/hip_runtime.h>
#include <hip/hip_bf16.h>

// Grouped conv2d as implicit GEMM per group:
//   out[b*64+co][h][w] = sum_{ci,kh,kw} W[b*64+co][ci][kh][kw] * x[b*64+ci][h+kh-1][w+kw-1]
// bf16 MFMA (16x16x32), fp32 accumulate.
//
// R16 = R13 (verified best: 335us rocprof / 289.6 bench, 96 VGPR, 0 conflicts)
// + two micro-deltas:
//  (a) depth-3 staging ping-pong (va/vb/vc, 24 live floats): 6 load8 rounds
//      at depth-2 = 3 serialized HBM/L3 latency rounds -> depth-3 = 2.
//      R8 ran this exact pattern at 104 VGPR, no spill; R13 is at 96.
//  (b) s_setprio(1) around the compute phase: 2 blocks/CU stagger naturally
//      (one stages while the other computes) -> T5's role-split prerequisite
//      holds across blocks; favor the computing wave on the SIMD.
// Everything else byte-identical to R13 (af-LDS broadcast via gload16,
// verified swizzle, ping-pong staging, epilogue).

typedef __bf16 bf16x8 __attribute__((ext_vector_type(8)));
typedef float  f32x4  __attribute__((ext_vector_type(4)));

#define NB 32
#define NH 256
#define NW 256
#define TILE_H 4
#define TILE_W 64
#define XROWS 6     // TILE_H + 2 (halo)
#define XCOLS 68    // TILE_W + 2, padded
#define HWSZ ((size_t)NH * NW)

__device__ __forceinline__ void gload16(const float* g, float* lds) {
    __builtin_amdgcn_global_load_lds(
        (const __attribute__((address_space(1))) unsigned int*)g,
        (__attribute__((address_space(3))) unsigned int*)lds, 16, 0, 0);
}

// ---------------------------------------------------------------------------
// Repack weights into MFMA A-fragment order:
//   pk[((b*9+tap)*4+mt)*2+kc][lane][j]  (bf16, 16B per lane)
// value = W[b*64 + mt*16 + (lane&15)][kc*32 + (lane>>4)*8 + j][tap]
// ---------------------------------------------------------------------------
__global__ void repack_weights_kernel(const float* __restrict__ wsrc,
                                      __bf16* __restrict__ pk) {
    int t = blockIdx.x * blockDim.x + threadIdx.x;
    if (t >= NB * 9 * 4 * 2 * 64) return;
    int lane = t & 63;
    int r = t >> 6;
    int kc = r & 1;  r >>= 1;
    int mt = r & 3;  r >>= 2;
    int tap = r % 9;
    int b   = r / 9;
    int co  = b * 64 + mt * 16 + (lane & 15);
    int ci0 = kc * 32 + (lane >> 4) * 8;
    bf16x8 v;
#pragma unroll
    for (int j = 0; j < 8; ++j) {
        v[j] = (__bf16)wsrc[(co * 64 + ci0 + j) * 9 + tap];
    }
    *reinterpret_cast<bf16x8*>(pk + (size_t)t * 8) = v;
}

// ---------------------------------------------------------------------------
// Main conv kernel. Block = (group b, 4 output rows, 64 output cols), 4 waves.
// xs: [r][c][32] bf16, octet of local ci o stored at 8*(o ^ ((c>>1)&3)).
// afs: 36 fragments (tap*4+mt) x 512 bf16, lane-linear; refilled per kc phase.
// ---------------------------------------------------------------------------
__launch_bounds__(256)
__global__ void conv_mfma_kernel(const float* __restrict__ x,
                                 const __bf16* __restrict__ pk,
                                 float* __restrict__ out) {
    __shared__ __align__(16) __bf16 xs[XROWS * XCOLS * 32];   // 26112 B
    __shared__ __align__(16) __bf16 afs[36 * 512];            // 36864 B

    // XCD-aware bijective swizzle: 8192 blocks, 8 XCDs
    const int orig = blockIdx.x;
    const int wg   = (orig & 7) * 1024 + (orig >> 3);
    const int b    = wg >> 8;            // 0..31
    const int by   = (wg >> 2) & 63;     // 0..63
    const int bx   = wg & 3;             // 0..3
    const int h0   = by * TILE_H;
    const int w0   = bx * TILE_W;

    const int tid  = threadIdx.x;
    const int wid  = tid >> 6;
    const int lane = tid & 63;
    const int nl   = lane & 15;
    const int kgrp = lane >> 4;          // 0..3

    const char* pkb = (const char*)(pk + (size_t)b * 9 * 4096);  // byte base

    // ---- af copy for phase kcv: 9 x 1KB gload16 per wave, zero registers ----
    auto issue_af = [&](int kcv) {
#pragma unroll
        for (int i = 0; i < 9; ++i) {
            const int f  = wid * 9 + i;       // fragment 0..35
            const int tp = f >> 2;
            const int mt = f & 3;
            const float* src = (const float*)(pkb + tp * 8192
                                              + (mt * 2 + kcv) * 1024 + lane * 16);
            gload16(src, (float*)((char*)afs + f * 1024));
        }
    };

    f32x4 acc[4][4];   // [mt][q]
#pragma unroll
    for (int mt = 0; mt < 4; ++mt)
#pragma unroll
        for (int q = 0; q < 4; ++q)
            acc[mt][q] = (f32x4){0.f, 0.f, 0.f, 0.f};

    // staging thread constants (main region: thread = column c = lane, oct = wid)
    const int c    = lane;               // 0..63 -> w = w0-1+c
    const int w    = w0 - 1 + c;
    const int wcl  = min(max(w, 0), NW - 1);
    const bool wbad = (w != wcl);
    const int sciw = ((wid ^ ((c >> 1) & 3)) * 8);   // swizzled octet offset

    // halo thread constants (threads 0..47: c=64,65)
    const int hr    = tid >> 3;              // 0..5
    const int hside = (tid >> 2) & 1;        // 0,1 -> c = 64,65
    const int hoct  = tid & 3;               // local ci octet
    const int hch   = 64 + hside;
    const int hw    = w0 + 63 + hside;
    const int hwc   = min(hw, NW - 1);

#pragma unroll
    for (int kc = 0; kc < 2; ++kc) {
        // ---- stage phase kc: af copy (fire-and-forget) + 32-ci x tile ----
        {
            issue_af(kc);

            const int cibase = b * 64 + kc * 32 + wid * 8;
            const float* colp = x + (size_t)cibase * HWSZ + wcl;

            // halo loads first (threads 0..47), store at end
            float hv[8];
            if (tid < 48) {
                const int h  = h0 - 1 + hr;
                const int hc = min(max(h, 0), NH - 1);
                const float* src = x + ((size_t)(b * 64 + kc * 32 + hoct * 8) * NH + hc) * NW + hwc;
#pragma unroll
                for (int j = 0; j < 8; ++j) hv[j] = src[j * HWSZ];
                if (h != hc || hw != hwc) {
#pragma unroll
                    for (int j = 0; j < 8; ++j) hv[j] = 0.f;
                }
            }

            float va[8], vb[8], vc[8];
            auto load8 = [&](int r, float* v) {
                const int h  = h0 - 1 + r;
                const int hc = min(max(h, 0), NH - 1);
                const float* src = colp + (size_t)hc * NW;
#pragma unroll
                for (int j = 0; j < 8; ++j) v[j] = src[j * HWSZ];
                if (wbad || h != hc) {
#pragma unroll
                    for (int j = 0; j < 8; ++j) v[j] = 0.f;
                }
            };
            auto store8 = [&](int r, const float* v) {
                bf16x8 o;
#pragma unroll
                for (int j = 0; j < 8; ++j) o[j] = (__bf16)v[j];
                *reinterpret_cast<bf16x8*>(xs + (r * XCOLS + c) * 32 + sciw) = o;
            };

            // depth-3 ping-pong: 2 serialized latency rounds instead of 3
            load8(0, va);
            load8(1, vb);
            load8(2, vc);
            store8(0, va); load8(3, va);
            store8(1, vb); load8(4, vb);
            store8(2, vc); load8(5, vc);
            store8(3, va);
            store8(4, vb);
            store8(5, vc);

            if (tid < 48) {
                bf16x8 o;
#pragma unroll
                for (int j = 0; j < 8; ++j) o[j] = (__bf16)hv[j];
                // slot(64)=slot(65)=0 -> octet position = hoct
                *reinterpret_cast<bf16x8*>(xs + (hr * XCOLS + hch) * 32 + hoct * 8) = o;
            }
        }
        __syncthreads();    // drains vmcnt: afs + xs both ready

        // ---- compute phase kc: 9 taps, VMEM-silent; af via ds_read_b128 ----
        __builtin_amdgcn_s_setprio(1);
#pragma unroll
        for (int tap = 0; tap < 9; ++tap) {
            bf16x8 afr[4];
#pragma unroll
            for (int mt = 0; mt < 4; ++mt)
                afr[mt] = *reinterpret_cast<const bf16x8*>(
                    afs + (tap * 4 + mt) * 512 + lane * 8);
            const int kh = tap / 3;
            const int kw = tap - kh * 3;
            const int rowbase = (wid + kh) * XCOLS;
#pragma unroll
            for (int q = 0; q < 4; ++q) {
                const int cc   = q * 16 + nl + kw;          // 0..65
                const int slot = (cc >> 1) & 3;
                bf16x8 bfv = *reinterpret_cast<const bf16x8*>(
                    xs + (rowbase + cc) * 32 + ((kgrp ^ slot) * 8));
#pragma unroll
                for (int mt = 0; mt < 4; ++mt)
                    acc[mt][q] = __builtin_amdgcn_mfma_f32_16x16x32_bf16(
                        afr[mt], bfv, acc[mt][q], 0, 0, 0);
            }
        }
        __builtin_amdgcn_s_setprio(0);
        if (kc == 0) __syncthreads();   // protect xs/afs before phase-1 refill
    }

    // ---- epilogue: D lane layout col=lane&15, row=(lane>>4)*4+reg ----
    const int mrow = kgrp * 4;
    const int h = h0 + wid;
#pragma unroll
    for (int mt = 0; mt < 4; ++mt) {
#pragma unroll
        for (int q = 0; q < 4; ++q) {
            const int ww = w0 + q * 16 + nl;
#pragma unroll
            for (int rg = 0; rg < 4; ++rg) {
                const int co = mt * 16 + mrow + rg;
                out[((size_t)(b * 64 + co) * NH + h) * NW + ww] = acc[mt][q][rg];
            }
        }
    }
}

extern "C" void kernel_launch(void* const* d_in, const int* in_sizes, int n_in,
                              void* d_out, int out_size, void* d_ws, size_t ws_size,
                              hipStream_t stream) {
    const float* x = (const float*)d_in[0];     // [1, 32*64, 256, 256] fp32
    const float* w = (const float*)d_in[1];     // [2048, 64, 3, 3] fp32
    float* out = (float*)d_out;                 // [1, 2048, 256, 256] fp32
    __bf16* pk = (__bf16*)d_ws;                 // 2.25 MB repacked bf16 weights

    {
        int total = NB * 9 * 4 * 2 * 64;        // 147456
        int blk = 256;
        int grid = (total + blk - 1) / blk;     // 576
        hipLaunchKernelGGL(repack_weights_kernel, dim3(grid), dim3(blk), 0, stream,
                           w, pk);
    }
    {
        dim3 grid(8192);                        // 1D, swizzled in-kernel
        hipLaunchKernelGGL(conv_mfma_kernel, grid, dim3(256), 0, stream,
                           x, pk, out);
    }
}

// Round 17
// 289.162 us; speedup vs baseline: 1.1642x; 1.0258x over previous
//
#include <hip/hip_runtime.h>
#include <hip/hip_bf16.h>

// Grouped conv2d as implicit GEMM per group:
//   out[b*64+co][h][w] = sum_{ci,kh,kw} W[b*64+co][ci][kh][kw] * x[b*64+ci][h+kh-1][w+kw-1]
// bf16 MFMA (16x16x32), fp32 accumulate.
//
// FINAL = R13 (best verified: 335us rocprof / 289.6us bench, 96 VGPR,
// 0 bank conflicts, clean traffic; R16's micro-deltas were neutral).
// Structure:
//  - weights repacked once into MFMA A-fragment order (bf16), broadcast
//    per-block through LDS via fire-and-forget global_load_lds (afs).
//  - x tile staged as bf16 into swizzled LDS (0-conflict layout, verified
//    by 8-lane-group bank analysis); register ping-pong staging (16 live
//    floats — within the acc+~30-VGPR spill budget established R5-R12).
//  - compute: 2 kc-phases x 9 taps, fully VMEM-silent (af via lane-linear
//    ds_read_b128, B-fragments via swizzled ds_read_b128), MFMA 16x16x32.
//  - XCD-aware bijective block swizzle; coalesced fp32 epilogue.

typedef __bf16 bf16x8 __attribute__((ext_vector_type(8)));
typedef float  f32x4  __attribute__((ext_vector_type(4)));

#define NB 32
#define NH 256
#define NW 256
#define TILE_H 4
#define TILE_W 64
#define XROWS 6     // TILE_H + 2 (halo)
#define XCOLS 68    // TILE_W + 2, padded
#define HWSZ ((size_t)NH * NW)

__device__ __forceinline__ void gload16(const float* g, float* lds) {
    __builtin_amdgcn_global_load_lds(
        (const __attribute__((address_space(1))) unsigned int*)g,
        (__attribute__((address_space(3))) unsigned int*)lds, 16, 0, 0);
}

// ---------------------------------------------------------------------------
// Repack weights into MFMA A-fragment order:
//   pk[((b*9+tap)*4+mt)*2+kc][lane][j]  (bf16, 16B per lane)
// value = W[b*64 + mt*16 + (lane&15)][kc*32 + (lane>>4)*8 + j][tap]
// ---------------------------------------------------------------------------
__global__ void repack_weights_kernel(const float* __restrict__ wsrc,
                                      __bf16* __restrict__ pk) {
    int t = blockIdx.x * blockDim.x + threadIdx.x;
    if (t >= NB * 9 * 4 * 2 * 64) return;
    int lane = t & 63;
    int r = t >> 6;
    int kc = r & 1;  r >>= 1;
    int mt = r & 3;  r >>= 2;
    int tap = r % 9;
    int b   = r / 9;
    int co  = b * 64 + mt * 16 + (lane & 15);
    int ci0 = kc * 32 + (lane >> 4) * 8;
    bf16x8 v;
#pragma unroll
    for (int j = 0; j < 8; ++j) {
        v[j] = (__bf16)wsrc[(co * 64 + ci0 + j) * 9 + tap];
    }
    *reinterpret_cast<bf16x8*>(pk + (size_t)t * 8) = v;
}

// ---------------------------------------------------------------------------
// Main conv kernel. Block = (group b, 4 output rows, 64 output cols), 4 waves.
// xs: [r][c][32] bf16, octet of local ci o stored at 8*(o ^ ((c>>1)&3)).
// afs: 36 fragments (tap*4+mt) x 512 bf16, lane-linear; refilled per kc phase.
// ---------------------------------------------------------------------------
__launch_bounds__(256)
__global__ void conv_mfma_kernel(const float* __restrict__ x,
                                 const __bf16* __restrict__ pk,
                                 float* __restrict__ out) {
    __shared__ __align__(16) __bf16 xs[XROWS * XCOLS * 32];   // 26112 B
    __shared__ __align__(16) __bf16 afs[36 * 512];            // 36864 B

    // XCD-aware bijective swizzle: 8192 blocks, 8 XCDs
    const int orig = blockIdx.x;
    const int wg   = (orig & 7) * 1024 + (orig >> 3);
    const int b    = wg >> 8;            // 0..31
    const int by   = (wg >> 2) & 63;     // 0..63
    const int bx   = wg & 3;             // 0..3
    const int h0   = by * TILE_H;
    const int w0   = bx * TILE_W;

    const int tid  = threadIdx.x;
    const int wid  = tid >> 6;
    const int lane = tid & 63;
    const int nl   = lane & 15;
    const int kgrp = lane >> 4;          // 0..3

    const char* pkb = (const char*)(pk + (size_t)b * 9 * 4096);  // byte base

    // ---- af copy for phase kcv: 9 x 1KB gload16 per wave, zero registers ----
    auto issue_af = [&](int kcv) {
#pragma unroll
        for (int i = 0; i < 9; ++i) {
            const int f  = wid * 9 + i;       // fragment 0..35
            const int tp = f >> 2;
            const int mt = f & 3;
            const float* src = (const float*)(pkb + tp * 8192
                                              + (mt * 2 + kcv) * 1024 + lane * 16);
            gload16(src, (float*)((char*)afs + f * 1024));
        }
    };

    f32x4 acc[4][4];   // [mt][q]
#pragma unroll
    for (int mt = 0; mt < 4; ++mt)
#pragma unroll
        for (int q = 0; q < 4; ++q)
            acc[mt][q] = (f32x4){0.f, 0.f, 0.f, 0.f};

    // staging thread constants (main region: thread = column c = lane, oct = wid)
    const int c    = lane;               // 0..63 -> w = w0-1+c
    const int w    = w0 - 1 + c;
    const int wcl  = min(max(w, 0), NW - 1);
    const bool wbad = (w != wcl);
    const int sciw = ((wid ^ ((c >> 1) & 3)) * 8);   // swizzled octet offset

    // halo thread constants (threads 0..47: c=64,65)
    const int hr    = tid >> 3;              // 0..5
    const int hside = (tid >> 2) & 1;        // 0,1 -> c = 64,65
    const int hoct  = tid & 3;               // local ci octet
    const int hch   = 64 + hside;
    const int hw    = w0 + 63 + hside;
    const int hwc   = min(hw, NW - 1);

#pragma unroll
    for (int kc = 0; kc < 2; ++kc) {
        // ---- stage phase kc: af copy (fire-and-forget) + 32-ci x tile ----
        {
            issue_af(kc);

            const int cibase = b * 64 + kc * 32 + wid * 8;
            const float* colp = x + (size_t)cibase * HWSZ + wcl;

            // halo loads first (threads 0..47), store at end
            float hv[8];
            if (tid < 48) {
                const int h  = h0 - 1 + hr;
                const int hc = min(max(h, 0), NH - 1);
                const float* src = x + ((size_t)(b * 64 + kc * 32 + hoct * 8) * NH + hc) * NW + hwc;
#pragma unroll
                for (int j = 0; j < 8; ++j) hv[j] = src[j * HWSZ];
                if (h != hc || hw != hwc) {
#pragma unroll
                    for (int j = 0; j < 8; ++j) hv[j] = 0.f;
                }
            }

            float va[8], vb[8];
            auto load8 = [&](int r, float* v) {
                const int h  = h0 - 1 + r;
                const int hc = min(max(h, 0), NH - 1);
                const float* src = colp + (size_t)hc * NW;
#pragma unroll
                for (int j = 0; j < 8; ++j) v[j] = src[j * HWSZ];
                if (wbad || h != hc) {
#pragma unroll
                    for (int j = 0; j < 8; ++j) v[j] = 0.f;
                }
            };
            auto store8 = [&](int r, const float* v) {
                bf16x8 o;
#pragma unroll
                for (int j = 0; j < 8; ++j) o[j] = (__bf16)v[j];
                *reinterpret_cast<bf16x8*>(xs + (r * XCOLS + c) * 32 + sciw) = o;
            };

            load8(0, va);
            load8(1, vb);
            store8(0, va); load8(2, va);
            store8(1, vb); load8(3, vb);
            store8(2, va); load8(4, va);
            store8(3, vb); load8(5, vb);
            store8(4, va);
            store8(5, vb);

            if (tid < 48) {
                bf16x8 o;
#pragma unroll
                for (int j = 0; j < 8; ++j) o[j] = (__bf16)hv[j];
                // slot(64)=slot(65)=0 -> octet position = hoct
                *reinterpret_cast<bf16x8*>(xs + (hr * XCOLS + hch) * 32 + hoct * 8) = o;
            }
        }
        __syncthreads();    // drains vmcnt: afs + xs both ready

        // ---- compute phase kc: 9 taps, VMEM-silent; af via ds_read_b128 ----
#pragma unroll
        for (int tap = 0; tap < 9; ++tap) {
            bf16x8 afr[4];
#pragma unroll
            for (int mt = 0; mt < 4; ++mt)
                afr[mt] = *reinterpret_cast<const bf16x8*>(
                    afs + (tap * 4 + mt) * 512 + lane * 8);
            const int kh = tap / 3;
            const int kw = tap - kh * 3;
            const int rowbase = (wid + kh) * XCOLS;
#pragma unroll
            for (int q = 0; q < 4; ++q) {
                const int cc   = q * 16 + nl + kw;          // 0..65
                const int slot = (cc >> 1) & 3;
                bf16x8 bfv = *reinterpret_cast<const bf16x8*>(
                    xs + (rowbase + cc) * 32 + ((kgrp ^ slot) * 8));
#pragma unroll
                for (int mt = 0; mt < 4; ++mt)
                    acc[mt][q] = __builtin_amdgcn_mfma_f32_16x16x32_bf16(
                        afr[mt], bfv, acc[mt][q], 0, 0, 0);
            }
        }
        if (kc == 0) __syncthreads();   // protect xs/afs before phase-1 refill
    }

    // ---- epilogue: D lane layout col=lane&15, row=(lane>>4)*4+reg ----
    const int mrow = kgrp * 4;
    const int h = h0 + wid;
#pragma unroll
    for (int mt = 0; mt < 4; ++mt) {
#pragma unroll
        for (int q = 0; q < 4; ++q) {
            const int ww = w0 + q * 16 + nl;
#pragma unroll
            for (int rg = 0; rg < 4; ++rg) {
                const int co = mt * 16 + mrow + rg;
                out[((size_t)(b * 64 + co) * NH + h) * NW + ww] = acc[mt][q][rg];
            }
        }
    }
}

extern "C" void kernel_launch(void* const* d_in, const int* in_sizes, int n_in,
                              void* d_out, int out_size, void* d_ws, size_t ws_size,
                              hipStream_t stream) {
    const float* x = (const float*)d_in[0];     // [1, 32*64, 256, 256] fp32
    const float* w = (const float*)d_in[1];     // [2048, 64, 3, 3] fp32
    float* out = (float*)d_out;                 // [1, 2048, 256, 256] fp32
    __bf16* pk = (__bf16*)d_ws;                 // 2.25 MB repacked bf16 weights

    {
        int total = NB * 9 * 4 * 2 * 64;        // 147456
        int blk = 256;
        int grid = (total + blk - 1) / blk;     // 576
        hipLaunchKernelGGL(repack_weights_kernel, dim3(grid), dim3(blk), 0, stream,
                           w, pk);
    }
    {
        dim3 grid(8192);                        // 1D, swizzled in-kernel
        hipLaunchKernelGGL(conv_mfma_kernel, grid, dim3(256), 0, stream,
                           x, pk, out);
    }
}